// Round 2
// baseline (404.330 us; speedup 1.0000x reference)
//
#include <hip/hip_runtime.h>
#include <hip/hip_bf16.h>

#define DEVINL __device__ __forceinline__

typedef __attribute__((ext_vector_type(4))) float f32x4;
typedef __attribute__((ext_vector_type(8))) short short8;

constexpr int CB = 2, CT = 2048, CD = 1024, CH = 16, CDK = 64;
constexpr int CM = CB * CT; // 4096 rows

DEVINL ushort f2bf(float f) {
  __hip_bfloat16 h = __float2bfloat16(f); // RNE
  ushort u; __builtin_memcpy(&u, &h, 2); return u;
}

// ---------------- f32 -> bf16 convert ----------------
__global__ void f32_to_bf16_kernel(const float* __restrict__ in, ushort* __restrict__ out, int n) {
  int i = (blockIdx.x * blockDim.x + threadIdx.x) * 4;
  const int stride = gridDim.x * blockDim.x * 4;
  for (; i < n; i += stride) {
    float4 v = *reinterpret_cast<const float4*>(in + i);
    ushort4 o;
    o.x = f2bf(v.x); o.y = f2bf(v.y); o.z = f2bf(v.z); o.w = f2bf(v.w);
    *reinterpret_cast<ushort4*>(out + i) = o;
  }
}

// ---------------- NT GEMM: C[i,j] = sum_k A[i,k]*Bm[j,k]  (bf16 in, f32 acc) ----------------
// mode 0: store bf16 to (B,H,T,DK)  [row i = b*T+t, col j = h*64+dk]
// mode 1: store bf16 to (B,H,DK,T)  (V transposed)
// mode 2: store f32 row-major MxN
__global__ __launch_bounds__(256, 2)
void gemm_nt_kernel(const ushort* __restrict__ A, const ushort* __restrict__ Bm,
                    const float* __restrict__ bias, void* __restrict__ Out,
                    int M, int N, int K, int mode, float scale)
{
  constexpr int BM = 128, BN = 128, BK = 32, LDT = 40; // pad 32->40: 2-way bank aliasing only
  __shared__ __align__(16) ushort As[BM * LDT];
  __shared__ __align__(16) ushort Bs[BN * LDT];
  const int tid = threadIdx.x;
  const int lane = tid & 63, wid = tid >> 6;
  const int wr = wid >> 1, wc = wid & 1;
  const int bm0 = blockIdx.y * BM, bn0 = blockIdx.x * BN;
  const int rsel = lane & 15, ksel = (lane >> 4) * 8;
  const int lrow = tid >> 2, lg = (tid & 3) * 8;

  f32x4 acc[4][4];
  for (int i = 0; i < 4; ++i) for (int j = 0; j < 4; ++j) acc[i][j] = f32x4{0.f, 0.f, 0.f, 0.f};

  for (int k0 = 0; k0 < K; k0 += BK) {
    __syncthreads();
    for (int p = 0; p < 2; ++p) {
      int r = p * 64 + lrow;
      *reinterpret_cast<short8*>(&As[r * LDT + lg]) =
          *reinterpret_cast<const short8*>(&A[(size_t)(bm0 + r) * K + k0 + lg]);
      *reinterpret_cast<short8*>(&Bs[r * LDT + lg]) =
          *reinterpret_cast<const short8*>(&Bm[(size_t)(bn0 + r) * K + k0 + lg]);
    }
    __syncthreads();
    short8 af[4], bfr[4];
    for (int mi = 0; mi < 4; ++mi)
      af[mi] = *reinterpret_cast<short8*>(&As[(wr * 64 + mi * 16 + rsel) * LDT + ksel]);
    for (int ni = 0; ni < 4; ++ni)
      bfr[ni] = *reinterpret_cast<short8*>(&Bs[(wc * 64 + ni * 16 + rsel) * LDT + ksel]);
    for (int mi = 0; mi < 4; ++mi)
      for (int ni = 0; ni < 4; ++ni)
        acc[mi][ni] = __builtin_amdgcn_mfma_f32_16x16x32_bf16(af[mi], bfr[ni], acc[mi][ni], 0, 0, 0);
  }

  const int r0 = (lane >> 4) * 4;
  for (int mi = 0; mi < 4; ++mi)
    for (int ni = 0; ni < 4; ++ni) {
      int gj = bn0 + wc * 64 + ni * 16 + rsel;
      float bv = bias[gj];
      for (int r = 0; r < 4; ++r) {
        int gi = bm0 + wr * 64 + mi * 16 + r0 + r;
        float v = (acc[mi][ni][r] + bv) * scale;
        if (mode == 2) {
          reinterpret_cast<float*>(Out)[(size_t)gi * N + gj] = v;
        } else {
          int bb = gi >> 11, t = gi & (CT - 1), h = gj >> 6, dk = gj & 63;
          size_t idx = (mode == 0)
              ? (((size_t)(bb * CH + h) * CT + t) * CDK + dk)
              : (((size_t)(bb * CH + h) * CDK + dk) * CT + t);
          reinterpret_cast<ushort*>(Out)[idx] = f2bf(v);
        }
      }
    }
}

// ---------------- fused attention: scores -> softmax -> attn write + PV ----------------
// grid: (T/64, B*H). 4 waves/block, each wave owns 16 q-rows.
// Qb: (B,H,T,DK) bf16 with the 1/8 scale folded in. Kb: (B,H,T,DK). Vt: (B,H,DK,T).
__global__ __launch_bounds__(256, 2)
void attn_kernel(const ushort* __restrict__ Qb, const ushort* __restrict__ Kb,
                 const ushort* __restrict__ Vt, const int* __restrict__ mask,
                 float* __restrict__ attn_out, ushort* __restrict__ oh)
{
  constexpr int KB = 64, LDK = 72; // pad 64->72 bf16 (144B rows): 2-way aliasing
  __shared__ __align__(16) ushort Ks[KB * LDK];
  __shared__ __align__(16) ushort Vs[CDK * LDK];
  __shared__ __align__(16) ushort Ps[4][16 * LDK]; // per-wave P tile 16x64

  const int tid = threadIdx.x, wid = tid >> 6, lane = tid & 63;
  const int bh = blockIdx.y, b = bh >> 4, h = bh & 15;
  const int q0 = blockIdx.x * 64 + wid * 16;
  const int rsel = lane & 15, grp = lane >> 4, ksel = grp * 8;
  const int srow = tid >> 3, scol = (tid & 7) * 8; // staging: 32 rows x 64 cols per pass

  // Q fragments held in registers for the whole kernel (A-frag: i=lane&15, k=grp*8+r)
  short8 qa0, qa1;
  {
    const ushort* qrow = Qb + ((size_t)bh * CT + q0 + rsel) * CDK;
    qa0 = *reinterpret_cast<const short8*>(qrow + ksel);
    qa1 = *reinterpret_cast<const short8*>(qrow + 32 + ksel);
  }

  float m_run[4], l_run[4];
  for (int r = 0; r < 4; ++r) { m_run[r] = -INFINITY; l_run[r] = 0.f; }
  const int* mrow = mask + (size_t)b * CT * CT;

  // ---- pass 1: row max + sum(exp) ----
  for (int k0 = 0; k0 < CT; k0 += KB) {
    __syncthreads();
    for (int p = 0; p < 2; ++p) {
      int r = p * 32 + srow;
      *reinterpret_cast<short8*>(&Ks[r * LDK + scol]) =
          *reinterpret_cast<const short8*>(&Kb[((size_t)bh * CT + k0 + r) * CDK + scol]);
    }
    __syncthreads();
    f32x4 s[4];
    for (int ni = 0; ni < 4; ++ni) {
      f32x4 z = {0.f, 0.f, 0.f, 0.f};
      short8 kb0 = *reinterpret_cast<short8*>(&Ks[(ni * 16 + rsel) * LDK + ksel]);
      short8 kb1 = *reinterpret_cast<short8*>(&Ks[(ni * 16 + rsel) * LDK + 32 + ksel]);
      z = __builtin_amdgcn_mfma_f32_16x16x32_bf16(qa0, kb0, z, 0, 0, 0);
      z = __builtin_amdgcn_mfma_f32_16x16x32_bf16(qa1, kb1, z, 0, 0, 0);
      s[ni] = z;
    }
    float tmax[4] = {-INFINITY, -INFINITY, -INFINITY, -INFINITY};
    for (int ni = 0; ni < 4; ++ni) {
      int kk = k0 + ni * 16 + rsel;
      for (int r = 0; r < 4; ++r) {
        int q = q0 + grp * 4 + r;
        float sv = mrow[(size_t)q * CT + kk] ? s[ni][r] : -INFINITY;
        s[ni][r] = sv;
        tmax[r] = fmaxf(tmax[r], sv);
      }
    }
    for (int off = 1; off < 16; off <<= 1)
      for (int r = 0; r < 4; ++r) tmax[r] = fmaxf(tmax[r], __shfl_xor(tmax[r], off, 64));
    float m2[4], tsum[4] = {0.f, 0.f, 0.f, 0.f};
    for (int r = 0; r < 4; ++r) m2[r] = fmaxf(m_run[r], tmax[r]);
    for (int ni = 0; ni < 4; ++ni)
      for (int r = 0; r < 4; ++r)
        tsum[r] += (m2[r] == -INFINITY) ? 0.f : __expf(s[ni][r] - m2[r]);
    for (int off = 1; off < 16; off <<= 1)
      for (int r = 0; r < 4; ++r) tsum[r] += __shfl_xor(tsum[r], off, 64);
    for (int r = 0; r < 4; ++r) {
      if (m2[r] > -INFINITY) {
        l_run[r] = l_run[r] * __expf(m_run[r] - m2[r]) + tsum[r];
        m_run[r] = m2[r];
      }
    }
  }

  float inv_l[4];
  for (int r = 0; r < 4; ++r) inv_l[r] = 1.f / l_run[r];
  f32x4 oacc[4];
  for (int nd = 0; nd < 4; ++nd) oacc[nd] = f32x4{0.f, 0.f, 0.f, 0.f};
  float* arow = attn_out + (size_t)bh * CT * CT;
  ushort* pw = &Ps[wid][0];

  // ---- pass 2: recompute scores, write attn, PV accumulate ----
  for (int k0 = 0; k0 < CT; k0 += KB) {
    __syncthreads();
    for (int p = 0; p < 2; ++p) {
      int r = p * 32 + srow;
      *reinterpret_cast<short8*>(&Ks[r * LDK + scol]) =
          *reinterpret_cast<const short8*>(&Kb[((size_t)bh * CT + k0 + r) * CDK + scol]);
      *reinterpret_cast<short8*>(&Vs[r * LDK + scol]) =
          *reinterpret_cast<const short8*>(&Vt[((size_t)bh * CDK + r) * CT + k0 + scol]);
    }
    __syncthreads();
    f32x4 s[4];
    for (int ni = 0; ni < 4; ++ni) {
      f32x4 z = {0.f, 0.f, 0.f, 0.f};
      short8 kb0 = *reinterpret_cast<short8*>(&Ks[(ni * 16 + rsel) * LDK + ksel]);
      short8 kb1 = *reinterpret_cast<short8*>(&Ks[(ni * 16 + rsel) * LDK + 32 + ksel]);
      z = __builtin_amdgcn_mfma_f32_16x16x32_bf16(qa0, kb0, z, 0, 0, 0);
      z = __builtin_amdgcn_mfma_f32_16x16x32_bf16(qa1, kb1, z, 0, 0, 0);
      s[ni] = z;
    }
    for (int ni = 0; ni < 4; ++ni) {
      int kk = k0 + ni * 16 + rsel;
      for (int r = 0; r < 4; ++r) {
        int q = q0 + grp * 4 + r;
        float p = mrow[(size_t)q * CT + kk] ? __expf(s[ni][r] - m_run[r]) : 0.f;
        arow[(size_t)q * CT + kk] = p * inv_l[r];
        pw[(grp * 4 + r) * LDK + ni * 16 + rsel] = f2bf(p); // wave-private LDS
      }
    }
    // re-fragment P as MFMA A-operand (same-wave LDS round trip; compiler inserts lgkmcnt)
    short8 pa0 = *reinterpret_cast<short8*>(&pw[rsel * LDK + ksel]);
    short8 pa1 = *reinterpret_cast<short8*>(&pw[rsel * LDK + 32 + ksel]);
    for (int nd = 0; nd < 4; ++nd) {
      short8 vb0 = *reinterpret_cast<short8*>(&Vs[(nd * 16 + rsel) * LDK + ksel]);
      short8 vb1 = *reinterpret_cast<short8*>(&Vs[(nd * 16 + rsel) * LDK + 32 + ksel]);
      oacc[nd] = __builtin_amdgcn_mfma_f32_16x16x32_bf16(pa0, vb0, oacc[nd], 0, 0, 0);
      oacc[nd] = __builtin_amdgcn_mfma_f32_16x16x32_bf16(pa1, vb1, oacc[nd], 0, 0, 0);
    }
  }

  // out_heads (B,T,D) bf16, normalized by 1/l
  for (int nd = 0; nd < 4; ++nd)
    for (int r = 0; r < 4; ++r) {
      int q = q0 + grp * 4 + r, d = nd * 16 + rsel;
      oh[((size_t)b * CT + q) * CD + h * CDK + d] = f2bf(oacc[nd][r] * inv_l[r]);
    }
}

// ---------------- launcher ----------------
extern "C" void kernel_launch(void* const* d_in, const int* in_sizes, int n_in,
                              void* d_out, int out_size, void* d_ws, size_t ws_size,
                              hipStream_t stream)
{
  const float* x_q  = (const float*)d_in[0];
  const float* x_kv = (const float*)d_in[1];
  const int*   mask = (const int*)d_in[2];
  const float* Wq = (const float*)d_in[3];
  const float* bq = (const float*)d_in[4];
  const float* Wk = (const float*)d_in[5];
  const float* bk = (const float*)d_in[6];
  const float* Wv = (const float*)d_in[7];
  const float* bv = (const float*)d_in[8];
  const float* Wo = (const float*)d_in[9];
  const float* bo = (const float*)d_in[10];

  float* out  = (float*)d_out;
  float* attn = out + (size_t)CB * CT * CD;

  char* w = (char*)d_ws;
  auto alloc = [&](size_t bytes) { char* p = w; w += (bytes + 255) & ~(size_t)255; return p; };
  ushort* xq_bf  = (ushort*)alloc((size_t)CM * CD * 2);
  ushort* xkv_bf = (ushort*)alloc((size_t)CM * CD * 2);
  ushort* Wq_bf  = (ushort*)alloc((size_t)CD * CD * 2);
  ushort* Wk_bf  = (ushort*)alloc((size_t)CD * CD * 2);
  ushort* Wv_bf  = (ushort*)alloc((size_t)CD * CD * 2);
  ushort* Wo_bf  = (ushort*)alloc((size_t)CD * CD * 2);
  ushort* Q_bf   = (ushort*)alloc((size_t)CM * CD * 2);
  ushort* K_bf   = (ushort*)alloc((size_t)CM * CD * 2);
  ushort* Vt_bf  = (ushort*)alloc((size_t)CM * CD * 2);
  ushort* oh_bf  = (ushort*)alloc((size_t)CM * CD * 2);

  auto cvt = [&](const float* src, ushort* dst, int n) {
    int blocks = (n / 4 + 255) / 256;
    if (blocks > 2048) blocks = 2048;
    hipLaunchKernelGGL(f32_to_bf16_kernel, dim3(blocks), dim3(256), 0, stream, src, dst, n);
  };
  cvt(x_q,  xq_bf,  CM * CD);
  cvt(x_kv, xkv_bf, CM * CD);
  cvt(Wq, Wq_bf, CD * CD);
  cvt(Wk, Wk_bf, CD * CD);
  cvt(Wv, Wv_bf, CD * CD);
  cvt(Wo, Wo_bf, CD * CD);

  dim3 gproj(CD / 128, CM / 128); // (8, 32)
  // Q carries the 1/sqrt(DK)=0.125 scale (exact power of two, applied after bias)
  hipLaunchKernelGGL(gemm_nt_kernel, gproj, dim3(256), 0, stream, xq_bf,  Wq_bf, bq, (void*)Q_bf,  CM, CD, CD, 0, 0.125f);
  hipLaunchKernelGGL(gemm_nt_kernel, gproj, dim3(256), 0, stream, xkv_bf, Wk_bf, bk, (void*)K_bf,  CM, CD, CD, 0, 1.0f);
  hipLaunchKernelGGL(gemm_nt_kernel, gproj, dim3(256), 0, stream, xkv_bf, Wv_bf, bv, (void*)Vt_bf, CM, CD, CD, 1, 1.0f);

  hipLaunchKernelGGL(attn_kernel, dim3(CT / 64, CB * CH), dim3(256), 0, stream,
                     Q_bf, K_bf, Vt_bf, mask, attn, oh_bf);

  hipLaunchKernelGGL(gemm_nt_kernel, gproj, dim3(256), 0, stream, oh_bf, Wo_bf, bo, d_out, CM, CD, CD, 2, 1.0f);
}